// Round 3
// baseline (151.584 us; speedup 1.0000x reference)
//
#include <hip/hip_runtime.h>

// SupConLoss on MI355X. features: [4096, 2, 128] fp32; labels: [4096] int; out: 1 f32.
//
// R2 changes vs R1:
//  - k_negsum exploits symmetry of exp(logits): triangular 128x128 block-tile grid
//    (2080 blocks). Off-diagonal tiles contribute to row sums AND (via shuffle
//    col-reduction) to column sums. Halves MFMA+exp work, 2x block count.
//  - k_count/k_scan/k_scatter merged into single-block k_bucket (the serial
//    100-iteration global-latency scan was a suspected ~25us hidden cost).
//  - k_pairs SLICES 4 -> 8.
//
// ws layout (words are 4B):
//   [0, 2 MB)   nf       : 8192 x 128 bf16 (normalized, row i = v*4096 + b)
//   + neg_sum  : 8192 f32 (zeroed)
//   + total    : 1 f32    (zeroed)
//   + counts   : 100 int
//   + offsets  : 101 int
//   + classIdx : 4096 int

#define BATCH 4096
#define NN    8192
#define DD    128
#define NCLS  100
#define MAXR  192
#define NB    64      // 8192 / 128 row-blocks
#define NTILE (NB * (NB + 1) / 2)   // 2080

typedef __attribute__((ext_vector_type(8))) short bf16x8;
typedef __attribute__((ext_vector_type(4))) float f32x4;

__device__ __forceinline__ unsigned short f2bf(float f) {
    unsigned u = __float_as_uint(f);
    u += 0x7FFF + ((u >> 16) & 1);
    return (unsigned short)(u >> 16);
}

__global__ void k_zero(float* p, int n) {
    int i = blockIdx.x * 256 + threadIdx.x;
    if (i < n) p[i] = 0.0f;
}

__global__ void k_normalize(const float* __restrict__ feat, unsigned short* __restrict__ nf) {
    int wave = threadIdx.x >> 6, lane = threadIdx.x & 63;
    int row = blockIdx.x * 4 + wave;
    int v = row >> 12, b = row & (BATCH - 1);
    const float2* src = (const float2*)(feat + ((size_t)b * 2 + v) * DD);
    float2 x = src[lane];
    float ss = x.x * x.x + x.y * x.y;
    #pragma unroll
    for (int m = 32; m >= 1; m >>= 1) ss += __shfl_xor(ss, m, 64);
    float inv = rsqrtf(ss);
    ushort2 o;
    o.x = f2bf(x.x * inv);
    o.y = f2bf(x.y * inv);
    ((ushort2*)(nf + (size_t)row * DD))[lane] = o;
}

// ---- single-block class bucketing: count + scan + scatter in LDS ----
__global__ __launch_bounds__(256) void k_bucket(const int* __restrict__ labels,
                                                int* __restrict__ counts,
                                                int* __restrict__ offsets,
                                                int* __restrict__ classIdx) {
    __shared__ int cnt[NCLS], off[NCLS], cur[NCLS];
    int tid = threadIdx.x;
    for (int c = tid; c < NCLS; c += 256) cnt[c] = 0;
    __syncthreads();
    for (int b = tid; b < BATCH; b += 256) atomicAdd(&cnt[labels[b]], 1);
    __syncthreads();
    if (tid == 0) {
        int a = 0;
        for (int c = 0; c < NCLS; ++c) { off[c] = a; a += cnt[c]; }
    }
    __syncthreads();
    for (int c = tid; c < NCLS; c += 256) {
        cur[c] = 0;
        counts[c] = cnt[c];
        offsets[c] = off[c];
    }
    if (tid == 0) offsets[NCLS] = BATCH;
    __syncthreads();
    for (int b = tid; b < BATCH; b += 256) {
        int l = labels[b];
        int p = atomicAdd(&cur[l], 1);
        classIdx[off[l] + p] = b;
    }
}

// ---- pass 1: neg_sum[i] = sum_j exp(logit_ij) [lab(i)!=lab(j)], symmetric ----
// Triangular grid over 128x128 block tiles (bi <= bj). 4 waves in 2x2; wave tile 64x64.
// Off-diagonal tiles: row sums for i in bi-block AND col sums for j in bj-block.
__global__ __launch_bounds__(256, 3) void k_negsum(
        const unsigned short* __restrict__ nf,
        const int* __restrict__ labels,
        float* __restrict__ neg_sum) {
    // decode triangular tile index -> (bi, bj), bi <= bj
    int t = blockIdx.x;
    float ft = (float)t;
    int bi = (int)((2.0f * NB + 1.0f - sqrtf((2.0f * NB + 1.0f) * (2.0f * NB + 1.0f) - 8.0f * ft)) * 0.5f);
    if (bi >= NB) bi = NB - 1;
    // f(bi) = bi*(2*NB+1-bi)/2
    while (bi * (2 * NB + 1 - bi) / 2 > t) --bi;
    while ((bi + 1) * (2 * NB - bi) / 2 <= t) ++bi;
    int bj = bi + (t - bi * (2 * NB + 1 - bi) / 2);
    bool diag = (bi == bj);

    int wave = threadIdx.x >> 6, lane = threadIdx.x & 63;
    int wr = wave >> 1, wc = wave & 1;
    int q = lane >> 4, nq = lane & 15;
    int rowBase = bi * 128 + wr * 64;
    int colBase = bj * 128 + wc * 64;
    const bf16x8* nfv = (const bf16x8*)nf;

    // A frags: wave's 64 rows
    bf16x8 aF[4][4];
    #pragma unroll
    for (int rs = 0; rs < 4; ++rs) {
        int r = rowBase + rs * 16 + nq;
        #pragma unroll
        for (int s = 0; s < 4; ++s) aF[rs][s] = nfv[r * 16 + s * 4 + q];
    }
    int rlab[4][4];
    float rowsum[4][4];
    #pragma unroll
    for (int rs = 0; rs < 4; ++rs)
        #pragma unroll
        for (int rr = 0; rr < 4; ++rr) {
            rlab[rs][rr] = labels[(rowBase + rs * 16 + q * 4 + rr) & (BATCH - 1)];
            rowsum[rs][rr] = 0.0f;
        }

    f32x4 acc[4][4];
    #pragma unroll
    for (int rs = 0; rs < 4; ++rs)
        #pragma unroll
        for (int cs = 0; cs < 4; ++cs) acc[rs][cs] = (f32x4){0.f, 0.f, 0.f, 0.f};
    #pragma unroll
    for (int s = 0; s < 4; ++s) {
        bf16x8 bF[4];
        #pragma unroll
        for (int cs = 0; cs < 4; ++cs)
            bF[cs] = nfv[(colBase + cs * 16 + nq) * 16 + s * 4 + q];
        #pragma unroll
        for (int rs = 0; rs < 4; ++rs)
            #pragma unroll
            for (int cs = 0; cs < 4; ++cs)
                acc[rs][cs] = __builtin_amdgcn_mfma_f32_16x16x32_bf16(
                    aF[rs][s], bF[cs], acc[rs][cs], 0, 0, 0);
    }

    // epilogue: C/D layout col = lane&15, row = (lane>>4)*4 + reg
    #pragma unroll
    for (int cs = 0; cs < 4; ++cs) {
        int col = colBase + cs * 16 + nq;
        int cl = labels[col & (BATCH - 1)];
        float colsum = 0.0f;
        #pragma unroll
        for (int rs = 0; rs < 4; ++rs)
            #pragma unroll
            for (int rr = 0; rr < 4; ++rr) {
                float e = __expf(acc[rs][cs][rr] * (1.0f / 0.07f));
                float ev = (rlab[rs][rr] != cl) ? e : 0.0f;
                rowsum[rs][rr] += ev;
                colsum += ev;
            }
        if (!diag) {
            colsum += __shfl_xor(colsum, 16, 64);
            colsum += __shfl_xor(colsum, 32, 64);
            if (q == 0) atomicAdd(&neg_sum[col], colsum);
        }
    }
    #pragma unroll
    for (int rs = 0; rs < 4; ++rs)
        #pragma unroll
        for (int rr = 0; rr < 4; ++rr) {
            float vsum = rowsum[rs][rr];
            vsum += __shfl_xor(vsum, 1, 64);
            vsum += __shfl_xor(vsum, 2, 64);
            vsum += __shfl_xor(vsum, 4, 64);
            vsum += __shfl_xor(vsum, 8, 64);
            if (nq == 0) atomicAdd(&neg_sum[rowBase + rs * 16 + q * 4 + rr], vsum);
        }
}

// ---- pass 2: positive pairs only ----
#define SLICES 8
__global__ __launch_bounds__(256) void k_pairs(
        const unsigned short* __restrict__ nf,
        const int* __restrict__ counts, const int* __restrict__ offsets,
        const int* __restrict__ classIdx,
        const float* __restrict__ neg_sum,
        float* __restrict__ total) {
    __shared__ int s_rows[MAXR];
    __shared__ unsigned short s_feat[MAXR * 136];
    int c = blockIdx.x;
    int m = counts[c];
    int off = offsets[c];
    int twoM = 2 * m;
    int tid = threadIdx.x;
    int ldsRows = twoM < MAXR ? twoM : MAXR;

    for (int r = tid; r < twoM; r += 256) {
        int b = classIdx[off + (r < m ? r : r - m)];
        int row = (r < m) ? b : b + BATCH;
        if (r < MAXR) s_rows[r] = row;
    }
    __syncthreads();
    for (int ch = tid; ch < ldsRows * 16; ch += 256) {
        int r = ch >> 4, s = ch & 15;
        const uint4* src = (const uint4*)(nf + (size_t)s_rows[r] * DD);
        *(uint4*)&s_feat[r * 136 + s * 8] = src[s];
    }
    __syncthreads();

    float partial = 0.0f;
    unsigned P = (unsigned)twoM * (unsigned)twoM;
    for (unsigned t = blockIdx.y * 256 + tid; t < P; t += 256 * SLICES) {
        unsigned p = t / (unsigned)twoM;
        unsigned qq = t - p * (unsigned)twoM;
        if (p == qq) continue;
        float dot = 0.0f;
        if ((int)p < MAXR && (int)qq < MAXR) {
            #pragma unroll 4
            for (int s = 0; s < 16; ++s) {
                uint4 ua = *(const uint4*)&s_feat[p * 136 + s * 8];
                uint4 ub = *(const uint4*)&s_feat[qq * 136 + s * 8];
                const unsigned* pa = (const unsigned*)&ua;
                const unsigned* pb = (const unsigned*)&ub;
                #pragma unroll
                for (int w = 0; w < 4; ++w) {
                    float a0 = __uint_as_float(pa[w] << 16);
                    float a1 = __uint_as_float(pa[w] & 0xFFFF0000u);
                    float b0 = __uint_as_float(pb[w] << 16);
                    float b1 = __uint_as_float(pb[w] & 0xFFFF0000u);
                    dot = fmaf(a0, b0, dot);
                    dot = fmaf(a1, b1, dot);
                }
            }
        } else {   // overflow fallback (never taken for random labels)
            int rp = ((int)p < m) ? classIdx[off + p] : classIdx[off + p - m] + BATCH;
            int rq = ((int)qq < m) ? classIdx[off + qq] : classIdx[off + qq - m] + BATCH;
            for (int d = 0; d < DD; ++d) {
                float a = __uint_as_float(((unsigned)nf[(size_t)rp * DD + d]) << 16);
                float b = __uint_as_float(((unsigned)nf[(size_t)rq * DD + d]) << 16);
                dot = fmaf(a, b, dot);
            }
        }
        int rj = ((int)qq < m) ? classIdx[off + qq] : classIdx[off + qq - m] + BATCH;
        float ns = neg_sum[rj];
        float logit = dot * (1.0f / 0.07f);
        partial += logit - __logf(ns + __expf(logit));
    }
    #pragma unroll
    for (int mm = 32; mm >= 1; mm >>= 1) partial += __shfl_xor(partial, mm, 64);
    __shared__ float red[4];
    if ((tid & 63) == 0) red[tid >> 6] = partial;
    __syncthreads();
    if (tid == 0) atomicAdd(total, red[0] + red[1] + red[2] + red[3]);
}

__global__ void k_final(const float* __restrict__ total, float* __restrict__ out) {
    out[0] = -total[0] * (1.0f / (float)NN);
}

extern "C" void kernel_launch(void* const* d_in, const int* in_sizes, int n_in,
                              void* d_out, int out_size, void* d_ws, size_t ws_size,
                              hipStream_t stream) {
    const float* feat = (const float*)d_in[0];
    const int* labels = (const int*)d_in[1];
    unsigned short* nf = (unsigned short*)d_ws;
    float* neg_sum = (float*)((char*)d_ws + (size_t)NN * DD * sizeof(unsigned short));
    float* total   = neg_sum + NN;          // 1
    int* counts    = (int*)(total + 1);     // 100
    int* offsets   = counts + NCLS;         // 101
    int* classIdx  = offsets + NCLS + 1;    // 4096
    float* out = (float*)d_out;

    hipLaunchKernelGGL(k_zero, dim3((NN + 1 + 255) / 256), dim3(256), 0, stream, neg_sum, NN + 1);
    hipLaunchKernelGGL(k_normalize, dim3(NN / 4), dim3(256), 0, stream, feat, nf);
    hipLaunchKernelGGL(k_bucket, dim3(1), dim3(256), 0, stream, labels, counts, offsets, classIdx);
    hipLaunchKernelGGL(k_negsum, dim3(NTILE), dim3(256), 0, stream, nf, labels, neg_sum);
    hipLaunchKernelGGL(k_pairs, dim3(NCLS, SLICES), dim3(256), 0, stream,
                       nf, counts, offsets, classIdx, neg_sum, total);
    hipLaunchKernelGGL(k_final, dim3(1), dim3(1), 0, stream, total, out);
}